// Round 1
// baseline (373.955 us; speedup 1.0000x reference)
//
#include <hip/hip_runtime.h>
#include <cstdint>
#include <cstddef>

#define NFEAT 512
#define NH1   256
#define NH2   128

#define SCAN_BLOCK 256
#define SCAN_ELEMS 4
#define SCAN_TILE  (SCAN_BLOCK * SCAN_ELEMS)   // 1024

#define P_CHUNKS 128          // edge chunks for privatized histogram
#define HHALF    25088        // nodes per half (2*HHALF = 50176 >= N)
#define NP       (2 * HHALF)  // padded node count in hist rows

typedef __attribute__((ext_vector_type(8))) short short8;
typedef __attribute__((ext_vector_type(4))) float float4v;

__device__ __forceinline__ unsigned short f2bf(float f) {
    unsigned int u = __float_as_uint(f);
    u += 0x7fffu + ((u >> 16) & 1u);   // round-to-nearest-even
    return (unsigned short)(u >> 16);
}
__device__ __forceinline__ float bf2f(unsigned short u) {
    return __uint_as_float(((unsigned int)u) << 16);
}

__device__ __forceinline__ void load_lds16(const void* g, void* l) {
    __builtin_amdgcn_global_load_lds(
        (const __attribute__((address_space(1))) void*)g,
        (__attribute__((address_space(3))) void*)l, 16, 0, 0);
}

// ---------------- CSR build: LDS-privatized counting sort ----------------
// Phase A: per-(chunk,half) histogram in LDS, coalesced write to hist[c][d].
__global__ __launch_bounds__(256) void k_hist(const int* __restrict__ dst,
                                              int* __restrict__ hist, int E, int CE) {
    __shared__ int lh[HHALF];
    const int c    = blockIdx.x >> 1;
    const int hf   = blockIdx.x & 1;
    const int base = hf * HHALF;
    for (int i = threadIdx.x; i < HHALF; i += 256) lh[i] = 0;
    __syncthreads();
    const int lo = c * CE;
    const int hi = lo + CE < E ? lo + CE : E;
    for (int e = lo + (int)threadIdx.x; e < hi; e += 256) {
        const int d = dst[e] - base;
        if ((unsigned)d < (unsigned)HHALF) atomicAdd(&lh[d], 1);
    }
    __syncthreads();
    int* outp = hist + (size_t)c * NP + base;
    for (int i = threadIdx.x; i < HHALF; i += 256) outp[i] = lh[i];
}

// Phase B: degi[d] = sum_c hist[c][d]; fused dinv = rsqrt(deg+1).
__global__ void k_colreduce(const int* __restrict__ hist, int* __restrict__ degi,
                            float* __restrict__ dinv, int N) {
    const int d = blockIdx.x * blockDim.x + threadIdx.x;
    if (d >= N) return;
    int s = 0;
#pragma unroll 8
    for (int c = 0; c < P_CHUNKS; ++c) s += hist[(size_t)c * NP + d];
    degi[d] = s;
    dinv[d] = rsqrtf((float)(s + 1));   // +1 = self-loop
}

// Phase D: in-place column exclusive scan: hist[c][d] -> global base offset.
__global__ void k_coloffs(int* __restrict__ hist, const int* __restrict__ row_start,
                          int N) {
    const int d = blockIdx.x * blockDim.x + threadIdx.x;
    if (d >= N) return;
    int run = row_start[d];
    for (int c = 0; c < P_CHUNKS; ++c) {
        int* p = &hist[(size_t)c * NP + d];
        const int t = *p;
        *p = run;
        run += t;
    }
}

// Phase E: place edges. LDS cursor atomics only; plain scattered stores.
__global__ __launch_bounds__(256) void k_place(const int* __restrict__ src,
                                               const int* __restrict__ dst,
                                               const int* __restrict__ hist,
                                               int* __restrict__ csr_src, int E, int CE) {
    __shared__ int lcur[HHALF];
    const int c    = blockIdx.x >> 1;
    const int hf   = blockIdx.x & 1;
    const int base = hf * HHALF;
    const int* offp = hist + (size_t)c * NP + base;
    for (int i = threadIdx.x; i < HHALF; i += 256) lcur[i] = offp[i];
    __syncthreads();
    const int lo = c * CE;
    const int hi = lo + CE < E ? lo + CE : E;
    for (int e = lo + (int)threadIdx.x; e < hi; e += 256) {
        const int d = dst[e] - base;
        if ((unsigned)d < (unsigned)HHALF) {
            const int p = atomicAdd(&lcur[d], 1);   // LDS atomic (fast)
            csr_src[p] = src[e];
        }
    }
}

// ---- three-phase exclusive scan over degi[0..N) -> row_start ----
__global__ __launch_bounds__(SCAN_BLOCK) void k_scan1(
    const int* __restrict__ degi, int* __restrict__ blocksums, int N) {
    __shared__ int red[SCAN_BLOCK];
    const int t = threadIdx.x;
    const int base = blockIdx.x * SCAN_TILE + t * SCAN_ELEMS;
    int s = 0;
#pragma unroll
    for (int i = 0; i < SCAN_ELEMS; ++i) {
        const int idx = base + i;
        if (idx < N) s += degi[idx];
    }
    red[t] = s;
    __syncthreads();
    for (int off = SCAN_BLOCK / 2; off > 0; off >>= 1) {
        if (t < off) red[t] += red[t + off];
        __syncthreads();
    }
    if (t == 0) blocksums[blockIdx.x] = red[0];
}

__global__ __launch_bounds__(1024) void k_scan2(
    const int* __restrict__ blocksums, int* __restrict__ blockoffs,
    int* __restrict__ row_start, int nb, int N) {
    __shared__ int sm[1024];
    const int t = threadIdx.x;
    const int v = (t < nb) ? blocksums[t] : 0;
    sm[t] = v;
    __syncthreads();
    for (int off = 1; off < 1024; off <<= 1) {
        const int x = (t >= off) ? sm[t - off] : 0;
        __syncthreads();
        sm[t] += x;
        __syncthreads();
    }
    if (t < nb) blockoffs[t] = sm[t] - v;
    if (t == 1023) row_start[N] = sm[1023];
}

__global__ __launch_bounds__(SCAN_BLOCK) void k_scan3(
    const int* __restrict__ degi, const int* __restrict__ blockoffs,
    int* __restrict__ row_start, int N) {
    __shared__ int tsum[SCAN_BLOCK];
    const int t = threadIdx.x;
    const int base = blockIdx.x * SCAN_TILE + t * SCAN_ELEMS;
    int v[SCAN_ELEMS];
    int s = 0;
#pragma unroll
    for (int i = 0; i < SCAN_ELEMS; ++i) {
        const int idx = base + i;
        v[i] = (idx < N) ? degi[idx] : 0;
        s += v[i];
    }
    tsum[t] = s;
    __syncthreads();
    for (int off = 1; off < SCAN_BLOCK; off <<= 1) {
        const int x = (t >= off) ? tsum[t - off] : 0;
        __syncthreads();
        tsum[t] += x;
        __syncthreads();
    }
    int excl = blockoffs[blockIdx.x] + tsum[t] - s;
#pragma unroll
    for (int i = 0; i < SCAN_ELEMS; ++i) {
        const int idx = base + i;
        if (idx < N) row_start[idx] = excl;
        excl += v[i];
    }
}

// ---------------- conversions ----------------
__global__ void k_cvt_x(const float* __restrict__ x, const float* __restrict__ dinv,
                        unsigned short* __restrict__ xb, int Nrows, int Mp) {
    int i = blockIdx.x * blockDim.x + threadIdx.x;   // one thread per 4 elements
    int total = Mp * (NFEAT / 4);
    if (i >= total) return;
    int row = i / (NFEAT / 4);
    int q   = (i % (NFEAT / 4)) * 4;
    ushort4 o;
    if (row < Nrows) {
        const float w = dinv[row];
        const float4 v = *(const float4*)&x[(size_t)row * NFEAT + q];
        o.x = f2bf(v.x * w); o.y = f2bf(v.y * w);
        o.z = f2bf(v.z * w); o.w = f2bf(v.w * w);
    } else {
        o.x = 0; o.y = 0; o.z = 0; o.w = 0;
    }
    *(ushort4*)&xb[(size_t)row * NFEAT + q] = o;
}

__global__ void k_cvt_wt(const float* __restrict__ W, unsigned short* __restrict__ Wt,
                         int K, int Nc) {
    int i = blockIdx.x * blockDim.x + threadIdx.x;
    if (i >= K * Nc) return;
    int k = i / Nc, n = i % Nc;
    Wt[(size_t)n * K + k] = f2bf(W[(size_t)k * Nc + n]);
}

// ---------------- bf16 MFMA GEMM ----------------
__global__ __launch_bounds__(256) void gemm_bf16(
    const unsigned short* __restrict__ A, const unsigned short* __restrict__ Bt,
    unsigned short* __restrict__ C, int N, int K) {
    __shared__ unsigned short As[128 * 32];
    __shared__ unsigned short Bs[128 * 32];
    const int t    = threadIdx.x;
    const int wave = t >> 6, lane = t & 63;
    const int row0 = blockIdx.y * 128, col0 = blockIdx.x * 128;
    const int wm = (wave >> 1) * 64, wn = (wave & 1) * 64;
    const int sr = lane >> 2;
    const int sk = (lane & 3) * 8;
    const int quad = lane >> 4, l15 = lane & 15;

    const int ca = wave * 2;
    const unsigned short* gA0 = A  + (size_t)(row0 + ca * 16 + sr) * K + sk;
    const unsigned short* gA1 = gA0 + (size_t)16 * K;
    const unsigned short* gB0 = Bt + (size_t)(col0 + ca * 16 + sr) * K + sk;
    const unsigned short* gB1 = gB0 + (size_t)16 * K;
    unsigned short* lA0 = &As[ca * 512];
    unsigned short* lA1 = &As[(ca + 1) * 512];
    unsigned short* lB0 = &Bs[ca * 512];
    unsigned short* lB1 = &Bs[(ca + 1) * 512];

    float4v acc[4][4] = {};

    for (int k0 = 0; k0 < K; k0 += 32) {
        __syncthreads();
        load_lds16(gA0 + k0, lA0);
        load_lds16(gA1 + k0, lA1);
        load_lds16(gB0 + k0, lB0);
        load_lds16(gB1 + k0, lB1);
        __syncthreads();

        short8 a[4], b[4];
#pragma unroll
        for (int i = 0; i < 4; ++i) {
            a[i] = *(const short8*)&As[(wm + i * 16 + l15) * 32 + quad * 8];
            b[i] = *(const short8*)&Bs[(wn + i * 16 + l15) * 32 + quad * 8];
        }
#pragma unroll
        for (int mt = 0; mt < 4; ++mt)
#pragma unroll
            for (int nt = 0; nt < 4; ++nt)
                acc[mt][nt] = __builtin_amdgcn_mfma_f32_16x16x32_bf16(
                    a[mt], b[nt], acc[mt][nt], 0, 0, 0);
    }

    // C/D layout: col = lane&15, row = (lane>>4)*4 + reg   [m89-verified]
#pragma unroll
    for (int mt = 0; mt < 4; ++mt) {
#pragma unroll
        for (int nt = 0; nt < 4; ++nt) {
            const int c = col0 + wn + nt * 16 + l15;
#pragma unroll
            for (int r = 0; r < 4; ++r) {
                const int row = row0 + wm + mt * 16 + quad * 4 + r;
                C[(size_t)row * N + c] = f2bf(acc[mt][nt][r]);
            }
        }
    }
}

// ---------------- CSR gather aggregation (bf16 features, pre-scaled rows) ----
template <int F, bool RELU, bool OUTF32>
__global__ __launch_bounds__(256) void k_gather(
    const int* __restrict__ row_start, const int* __restrict__ csr_src,
    const float* __restrict__ dinv, const unsigned short* __restrict__ h,
    const float* __restrict__ bias, unsigned short* __restrict__ ob,
    float* __restrict__ of, int N) {
    const int gid  = blockIdx.x * blockDim.x + threadIdx.x;
    const int node = gid >> 6;
    const int lane = gid & 63;
    if (node >= N) return;

    constexpr int EL = F / 64;           // 4 (F=256) or 2 (F=128)
    const float wd = dinv[node];
    const int jb = row_start[node];
    const int je = row_start[node + 1];
    const unsigned short* hl = h + (size_t)lane * EL;

    float acc[EL];
    {   // self-loop term (h already dinv-scaled)
        const unsigned short* hp = hl + (size_t)node * F;
        if (EL == 4) {
            const ushort4 v = *(const ushort4*)hp;
            acc[0] = bf2f(v.x); acc[1] = bf2f(v.y);
            acc[2] = bf2f(v.z); acc[3] = bf2f(v.w);
        } else {
            const ushort2 v = *(const ushort2*)hp;
            acc[0] = bf2f(v.x); acc[1] = bf2f(v.y);
        }
    }

    for (int j0 = jb; j0 < je; j0 += 64) {
        int jj = j0 + lane;
        if (jj >= je) jj = je - 1;
        const int myi = csr_src[jj];
        const int rem = je - j0;
        const int cnt = rem < 64 ? rem : 64;
        int i = 0;
        for (; i + 4 <= cnt; i += 4) {   // 4 independent row loads in flight
            const int s0 = __shfl(myi, i + 0);
            const int s1 = __shfl(myi, i + 1);
            const int s2 = __shfl(myi, i + 2);
            const int s3 = __shfl(myi, i + 3);
            if (EL == 4) {
                const ushort4 v0 = *(const ushort4*)(hl + (size_t)s0 * F);
                const ushort4 v1 = *(const ushort4*)(hl + (size_t)s1 * F);
                const ushort4 v2 = *(const ushort4*)(hl + (size_t)s2 * F);
                const ushort4 v3 = *(const ushort4*)(hl + (size_t)s3 * F);
                acc[0] += bf2f(v0.x) + bf2f(v1.x) + bf2f(v2.x) + bf2f(v3.x);
                acc[1] += bf2f(v0.y) + bf2f(v1.y) + bf2f(v2.y) + bf2f(v3.y);
                acc[2] += bf2f(v0.z) + bf2f(v1.z) + bf2f(v2.z) + bf2f(v3.z);
                acc[3] += bf2f(v0.w) + bf2f(v1.w) + bf2f(v2.w) + bf2f(v3.w);
            } else {
                const ushort2 v0 = *(const ushort2*)(hl + (size_t)s0 * F);
                const ushort2 v1 = *(const ushort2*)(hl + (size_t)s1 * F);
                const ushort2 v2 = *(const ushort2*)(hl + (size_t)s2 * F);
                const ushort2 v3 = *(const ushort2*)(hl + (size_t)s3 * F);
                acc[0] += bf2f(v0.x) + bf2f(v1.x) + bf2f(v2.x) + bf2f(v3.x);
                acc[1] += bf2f(v0.y) + bf2f(v1.y) + bf2f(v2.y) + bf2f(v3.y);
            }
        }
        for (; i < cnt; ++i) {
            const int s = __shfl(myi, i);
            const unsigned short* hp = hl + (size_t)s * F;
            if (EL == 4) {
                const ushort4 v = *(const ushort4*)hp;
                acc[0] += bf2f(v.x); acc[1] += bf2f(v.y);
                acc[2] += bf2f(v.z); acc[3] += bf2f(v.w);
            } else {
                const ushort2 v = *(const ushort2*)hp;
                acc[0] += bf2f(v.x); acc[1] += bf2f(v.y);
            }
        }
    }

#pragma unroll
    for (int i = 0; i < EL; ++i) {
        float v = fmaf(acc[i], wd, bias[lane * EL + i]);
        if (OUTF32) {
            of[(size_t)node * F + lane * EL + i] = v;
        } else {
            if (RELU) v = fmaxf(v, 0.f);
            ob[(size_t)node * F + lane * EL + i] = f2bf(v * wd);  // pre-scale for next layer
        }
    }
}

extern "C" void kernel_launch(void* const* d_in, const int* in_sizes, int n_in,
                              void* d_out, int out_size, void* d_ws, size_t ws_size,
                              hipStream_t stream) {
    const float* x   = (const float*)d_in[0];
    const int*   ei  = (const int*)d_in[1];
    const float* W1  = (const float*)d_in[2];
    const float* b1  = (const float*)d_in[3];
    const float* W2  = (const float*)d_in[4];
    const float* b2  = (const float*)d_in[5];
    float*       out = (float*)d_out;

    const int N = in_sizes[0] / NFEAT;           // 50000
    const int E = in_sizes[1] / 2;               // 800000
    const int Mp = ((N + 127) / 128) * 128;      // 50048
    const int* srcp = ei;
    const int* dstp = ei + E;
    const int nScanBlocks = (N + SCAN_TILE - 1) / SCAN_TILE;   // 49
    const int CE = (E + P_CHUNKS - 1) / P_CHUNKS;              // 6250

    // workspace layout (256B aligned chunks)
    char* wsb = (char*)d_ws;
    auto take = [&](size_t bytes) {
        char* p = wsb;
        wsb += (bytes + 255) & ~(size_t)255;
        return p;
    };
    int*   degi      = (int*)take((size_t)N * 4);
    int*   row_start = (int*)take((size_t)(N + 1) * 4);
    int*   csr_src   = (int*)take((size_t)E * 4);
    int*   blocksums = (int*)take((size_t)1024 * 4);
    int*   blockoffs = (int*)take((size_t)1024 * 4);
    float* dinv      = (float*)take((size_t)N * 4);
    unsigned short* xb  = (unsigned short*)take((size_t)Mp * NFEAT * 2);  // also h2
    unsigned short* W1t = (unsigned short*)take((size_t)NH1 * NFEAT * 2);
    unsigned short* W2t = (unsigned short*)take((size_t)NH2 * NH1 * 2);
    // union region: hist (25.7 MB, dead before GEMM1) overlaps h + h1 (51.2 MB)
    const size_t hBytes    = (size_t)Mp * NH1 * 2;
    const size_t histBytes = (size_t)P_CHUNKS * NP * 4;
    char* big = take(histBytes > 2 * hBytes ? histBytes : 2 * hBytes);
    int*            hist = (int*)big;
    unsigned short* h    = (unsigned short*)big;
    unsigned short* h1   = (unsigned short*)(big + hBytes);
    unsigned short* h2   = xb;                   // xb dead after GEMM1

    // ---- CSR build (atomic-free) + dinv ----
    k_hist<<<P_CHUNKS * 2, 256, 0, stream>>>(dstp, hist, E, CE);
    k_colreduce<<<(N + 255) / 256, 256, 0, stream>>>(hist, degi, dinv, N);
    k_scan1<<<nScanBlocks, SCAN_BLOCK, 0, stream>>>(degi, blocksums, N);
    k_scan2<<<1, 1024, 0, stream>>>(blocksums, blockoffs, row_start, nScanBlocks, N);
    k_scan3<<<nScanBlocks, SCAN_BLOCK, 0, stream>>>(degi, blockoffs, row_start, N);
    k_coloffs<<<(N + 255) / 256, 256, 0, stream>>>(hist, row_start, N);
    k_place<<<P_CHUNKS * 2, 256, 0, stream>>>(srcp, dstp, hist, csr_src, E, CE);

    // ---- conversions ----
    {
        int total = Mp * (NFEAT / 4);
        k_cvt_x<<<(total + 255) / 256, 256, 0, stream>>>(x, dinv, xb, N, Mp);
    }
    k_cvt_wt<<<(NFEAT * NH1 + 255) / 256, 256, 0, stream>>>(W1, W1t, NFEAT, NH1);
    k_cvt_wt<<<(NH1 * NH2 + 255) / 256, 256, 0, stream>>>(W2, W2t, NH1, NH2);

    // ---- layer 1: h = (x*dinv)@W1 (bf16) ; h1 = relu(...)*dinv (bf16) ----
    {
        dim3 g(NH1 / 128, Mp / 128);
        gemm_bf16<<<g, 256, 0, stream>>>(xb, W1t, h, NH1, NFEAT);
    }
    {
        int total = N * 64;
        k_gather<NH1, true, false><<<(total + 255) / 256, 256, 0, stream>>>(
            row_start, csr_src, dinv, h, b1, h1, nullptr, N);
    }

    // ---- layer 2: h2 = h1s@W2 (bf16) ; out = gather + b2 (fp32) ----
    {
        dim3 g(NH2 / 128, Mp / 128);
        gemm_bf16<<<g, 256, 0, stream>>>(h1, W2t, h2, NH2, NH1);
    }
    {
        int total = N * 64;
        k_gather<NH2, false, true><<<(total + 255) / 256, 256, 0, stream>>>(
            row_start, csr_src, dinv, h2, b2, nullptr, out, N);
    }
}

// Round 2
// 346.703 us; speedup vs baseline: 1.0786x; 1.0786x over previous
//
#include <hip/hip_runtime.h>
#include <cstdint>
#include <cstddef>

#define NFEAT 512
#define NH1   256
#define NH2   128

#define SCAN_BLOCK 256
#define SCAN_ELEMS 4
#define SCAN_TILE  (SCAN_BLOCK * SCAN_ELEMS)   // 1024

#define P_CHUNKS 128          // edge chunks for privatized histogram
#define HHALF    25088        // nodes per half (2*HHALF = 50176 >= N)
#define NP       (2 * HHALF)  // padded node count in hist rows

typedef __attribute__((ext_vector_type(8))) short short8;
typedef __attribute__((ext_vector_type(4))) float float4v;

__device__ __forceinline__ unsigned short f2bf(float f) {
    unsigned int u = __float_as_uint(f);
    u += 0x7fffu + ((u >> 16) & 1u);   // round-to-nearest-even
    return (unsigned short)(u >> 16);
}
__device__ __forceinline__ float bf2f(unsigned short u) {
    return __uint_as_float(((unsigned int)u) << 16);
}

__device__ __forceinline__ void load_lds16(const void* g, void* l) {
    __builtin_amdgcn_global_load_lds(
        (const __attribute__((address_space(1))) void*)g,
        (__attribute__((address_space(3))) void*)l, 16, 0, 0);
}

// ---------------- CSR build: LDS-privatized counting sort ----------------
// Phase A: per-(chunk,half) histogram in LDS, coalesced write to hist[c][d].
__global__ __launch_bounds__(256) void k_hist(const int* __restrict__ dst,
                                              int* __restrict__ hist, int E, int CE) {
    __shared__ int lh[HHALF];
    const int c    = blockIdx.x >> 1;
    const int hf   = blockIdx.x & 1;
    const int base = hf * HHALF;
    for (int i = threadIdx.x; i < HHALF; i += 256) lh[i] = 0;
    __syncthreads();
    const int lo = c * CE;
    const int hi = lo + CE < E ? lo + CE : E;
    for (int e = lo + (int)threadIdx.x; e < hi; e += 256) {
        const int d = dst[e] - base;
        if ((unsigned)d < (unsigned)HHALF) atomicAdd(&lh[d], 1);
    }
    __syncthreads();
    int* outp = hist + (size_t)c * NP + base;
    for (int i = threadIdx.x; i < HHALF; i += 256) outp[i] = lh[i];
}

// Phase B: degi[d] = sum_c hist[c][d]; fused dinv = rsqrt(deg+1).
__global__ void k_colreduce(const int* __restrict__ hist, int* __restrict__ degi,
                            float* __restrict__ dinv, int N) {
    const int d = blockIdx.x * blockDim.x + threadIdx.x;
    if (d >= N) return;
    int s = 0;
#pragma unroll 8
    for (int c = 0; c < P_CHUNKS; ++c) s += hist[(size_t)c * NP + d];
    degi[d] = s;
    dinv[d] = rsqrtf((float)(s + 1));   // +1 = self-loop
}

// Phase D: in-place column exclusive scan: hist[c][d] -> global base offset.
__global__ void k_coloffs(int* __restrict__ hist, const int* __restrict__ row_start,
                          int N) {
    const int d = blockIdx.x * blockDim.x + threadIdx.x;
    if (d >= N) return;
    int run = row_start[d];
    for (int c = 0; c < P_CHUNKS; ++c) {
        int* p = &hist[(size_t)c * NP + d];
        const int t = *p;
        *p = run;
        run += t;
    }
}

// Phase E: place edges. LDS cursor atomics only; plain scattered stores.
__global__ __launch_bounds__(256) void k_place(const int* __restrict__ src,
                                               const int* __restrict__ dst,
                                               const int* __restrict__ hist,
                                               int* __restrict__ csr_src, int E, int CE) {
    __shared__ int lcur[HHALF];
    const int c    = blockIdx.x >> 1;
    const int hf   = blockIdx.x & 1;
    const int base = hf * HHALF;
    const int* offp = hist + (size_t)c * NP + base;
    for (int i = threadIdx.x; i < HHALF; i += 256) lcur[i] = offp[i];
    __syncthreads();
    const int lo = c * CE;
    const int hi = lo + CE < E ? lo + CE : E;
    for (int e = lo + (int)threadIdx.x; e < hi; e += 256) {
        const int d = dst[e] - base;
        if ((unsigned)d < (unsigned)HHALF) {
            const int p = atomicAdd(&lcur[d], 1);   // LDS atomic (fast)
            csr_src[p] = src[e];
        }
    }
}

// ---- three-phase exclusive scan over degi[0..N) -> row_start ----
__global__ __launch_bounds__(SCAN_BLOCK) void k_scan1(
    const int* __restrict__ degi, int* __restrict__ blocksums, int N) {
    __shared__ int red[SCAN_BLOCK];
    const int t = threadIdx.x;
    const int base = blockIdx.x * SCAN_TILE + t * SCAN_ELEMS;
    int s = 0;
#pragma unroll
    for (int i = 0; i < SCAN_ELEMS; ++i) {
        const int idx = base + i;
        if (idx < N) s += degi[idx];
    }
    red[t] = s;
    __syncthreads();
    for (int off = SCAN_BLOCK / 2; off > 0; off >>= 1) {
        if (t < off) red[t] += red[t + off];
        __syncthreads();
    }
    if (t == 0) blocksums[blockIdx.x] = red[0];
}

__global__ __launch_bounds__(1024) void k_scan2(
    const int* __restrict__ blocksums, int* __restrict__ blockoffs,
    int* __restrict__ row_start, int nb, int N) {
    __shared__ int sm[1024];
    const int t = threadIdx.x;
    const int v = (t < nb) ? blocksums[t] : 0;
    sm[t] = v;
    __syncthreads();
    for (int off = 1; off < 1024; off <<= 1) {
        const int x = (t >= off) ? sm[t - off] : 0;
        __syncthreads();
        sm[t] += x;
        __syncthreads();
    }
    if (t < nb) blockoffs[t] = sm[t] - v;
    if (t == 1023) row_start[N] = sm[1023];
}

__global__ __launch_bounds__(SCAN_BLOCK) void k_scan3(
    const int* __restrict__ degi, const int* __restrict__ blockoffs,
    int* __restrict__ row_start, int N) {
    __shared__ int tsum[SCAN_BLOCK];
    const int t = threadIdx.x;
    const int base = blockIdx.x * SCAN_TILE + t * SCAN_ELEMS;
    int v[SCAN_ELEMS];
    int s = 0;
#pragma unroll
    for (int i = 0; i < SCAN_ELEMS; ++i) {
        const int idx = base + i;
        v[i] = (idx < N) ? degi[idx] : 0;
        s += v[i];
    }
    tsum[t] = s;
    __syncthreads();
    for (int off = 1; off < SCAN_BLOCK; off <<= 1) {
        const int x = (t >= off) ? tsum[t - off] : 0;
        __syncthreads();
        tsum[t] += x;
        __syncthreads();
    }
    int excl = blockoffs[blockIdx.x] + tsum[t] - s;
#pragma unroll
    for (int i = 0; i < SCAN_ELEMS; ++i) {
        const int idx = base + i;
        if (idx < N) row_start[idx] = excl;
        excl += v[i];
    }
}

// ---------------- weight conversion (both layers, one dispatch) ----------------
__global__ void k_cvt_w(const float* __restrict__ W1, unsigned short* __restrict__ W1t,
                        const float* __restrict__ W2, unsigned short* __restrict__ W2t) {
    const int i = blockIdx.x * blockDim.x + threadIdx.x;
    const int T1 = NFEAT * NH1;
    const int T2 = NH1 * NH2;
    if (i < T1) {
        const int k = i / NH1, n = i % NH1;
        W1t[(size_t)n * NFEAT + k] = f2bf(W1[i]);
    } else if (i < T1 + T2) {
        const int j = i - T1;
        const int k = j / NH2, n = j % NH2;
        W2t[(size_t)n * NH1 + k] = f2bf(W2[j]);
    }
}

// ---------------- fused layer-1 GEMM: h = bf16((x*dinv) @ W1) ----------------
// 128x256 tile, 8 waves (512 thr). A is reg-staged f32 -> *dinv -> bf16 -> LDS;
// B (W1t, 256x512 bf16 n-major) via global_load_lds. Single column block: A read once.
__global__ __launch_bounds__(512) void gemm_x_fused(
    const float* __restrict__ x, const float* __restrict__ dinv,
    const unsigned short* __restrict__ Bt, unsigned short* __restrict__ C,
    int Nrows, int K) {
    __shared__ unsigned short As[128 * 32];   //  8 KB
    __shared__ unsigned short Bs[256 * 32];   // 16 KB
    const int t    = threadIdx.x;
    const int wave = t >> 6, lane = t & 63;
    const int row0 = blockIdx.x * 128;
    const int quad = lane >> 4, l15 = lane & 15;
    const int wm = (wave >> 2) * 64;          // 0 / 64
    const int wn = (wave & 3) * 64;           // 0 / 64 / 128 / 192

    // A staging: thread t -> row t>>2 (0..127), k-offset (t&3)*8 (8 f32)
    const int arow = t >> 2;
    const int ak   = (t & 3) * 8;
    const int gr   = (row0 + arow < Nrows) ? row0 + arow : Nrows - 1;  // clamp pad rows
    const float wd = dinv[gr];
    const float* gx = x + (size_t)gr * K + ak;
    unsigned short* lA = &As[arow * 32 + ak];                 // byte off = t*16 (linear)

    // B staging: two global_load_lds segs; linear LDS [256][32] matches t*16 layout
    const int brow = t >> 2;                  // 0..127 (seg2: +128)
    const int bk   = (t & 3) * 8;
    const unsigned short* gB0 = Bt + (size_t)brow * K + bk;
    const unsigned short* gB1 = Bt + (size_t)(128 + brow) * K + bk;
    unsigned short* lB0 = &Bs[wave * 512];            // wave-uniform base + lane*16
    unsigned short* lB1 = &Bs[128 * 32 + wave * 512];

    float4v acc[4][4] = {};

    for (int k0 = 0; k0 < K; k0 += 32) {
        __syncthreads();
        load_lds16(gB0 + k0, lB0);
        load_lds16(gB1 + k0, lB1);
        const float4 v0 = *(const float4*)(gx + k0);
        const float4 v1 = *(const float4*)(gx + k0 + 4);
        short8 o;
        o[0] = (short)f2bf(v0.x * wd); o[1] = (short)f2bf(v0.y * wd);
        o[2] = (short)f2bf(v0.z * wd); o[3] = (short)f2bf(v0.w * wd);
        o[4] = (short)f2bf(v1.x * wd); o[5] = (short)f2bf(v1.y * wd);
        o[6] = (short)f2bf(v1.z * wd); o[7] = (short)f2bf(v1.w * wd);
        *(short8*)lA = o;                                   // 16B ds_write
        __syncthreads();

        short8 a[4], b[4];
#pragma unroll
        for (int i = 0; i < 4; ++i) {
            a[i] = *(const short8*)&As[(wm + i * 16 + l15) * 32 + quad * 8];
            b[i] = *(const short8*)&Bs[(wn + i * 16 + l15) * 32 + quad * 8];
        }
#pragma unroll
        for (int mt = 0; mt < 4; ++mt)
#pragma unroll
            for (int nt = 0; nt < 4; ++nt)
                acc[mt][nt] = __builtin_amdgcn_mfma_f32_16x16x32_bf16(
                    a[mt], b[nt], acc[mt][nt], 0, 0, 0);
    }

    // C/D layout: col = lane&15, row = (lane>>4)*4 + reg   [m89-verified]
#pragma unroll
    for (int mt = 0; mt < 4; ++mt) {
#pragma unroll
        for (int nt = 0; nt < 4; ++nt) {
            const int c = wn + nt * 16 + l15;
#pragma unroll
            for (int r = 0; r < 4; ++r) {
                const int row = row0 + wm + mt * 16 + quad * 4 + r;
                C[(size_t)row * NH1 + c] = f2bf(acc[mt][nt][r]);
            }
        }
    }
}

// ---------------- bf16 MFMA GEMM (layer 2) ----------------
__global__ __launch_bounds__(256) void gemm_bf16(
    const unsigned short* __restrict__ A, const unsigned short* __restrict__ Bt,
    unsigned short* __restrict__ C, int N, int K) {
    __shared__ unsigned short As[128 * 32];
    __shared__ unsigned short Bs[128 * 32];
    const int t    = threadIdx.x;
    const int wave = t >> 6, lane = t & 63;
    const int row0 = blockIdx.y * 128, col0 = blockIdx.x * 128;
    const int wm = (wave >> 1) * 64, wn = (wave & 1) * 64;
    const int sr = lane >> 2;
    const int sk = (lane & 3) * 8;
    const int quad = lane >> 4, l15 = lane & 15;

    const int ca = wave * 2;
    const unsigned short* gA0 = A  + (size_t)(row0 + ca * 16 + sr) * K + sk;
    const unsigned short* gA1 = gA0 + (size_t)16 * K;
    const unsigned short* gB0 = Bt + (size_t)(col0 + ca * 16 + sr) * K + sk;
    const unsigned short* gB1 = gB0 + (size_t)16 * K;
    unsigned short* lA0 = &As[ca * 512];
    unsigned short* lA1 = &As[(ca + 1) * 512];
    unsigned short* lB0 = &Bs[ca * 512];
    unsigned short* lB1 = &Bs[(ca + 1) * 512];

    float4v acc[4][4] = {};

    for (int k0 = 0; k0 < K; k0 += 32) {
        __syncthreads();
        load_lds16(gA0 + k0, lA0);
        load_lds16(gA1 + k0, lA1);
        load_lds16(gB0 + k0, lB0);
        load_lds16(gB1 + k0, lB1);
        __syncthreads();

        short8 a[4], b[4];
#pragma unroll
        for (int i = 0; i < 4; ++i) {
            a[i] = *(const short8*)&As[(wm + i * 16 + l15) * 32 + quad * 8];
            b[i] = *(const short8*)&Bs[(wn + i * 16 + l15) * 32 + quad * 8];
        }
#pragma unroll
        for (int mt = 0; mt < 4; ++mt)
#pragma unroll
            for (int nt = 0; nt < 4; ++nt)
                acc[mt][nt] = __builtin_amdgcn_mfma_f32_16x16x32_bf16(
                    a[mt], b[nt], acc[mt][nt], 0, 0, 0);
    }

    // C/D layout: col = lane&15, row = (lane>>4)*4 + reg   [m89-verified]
#pragma unroll
    for (int mt = 0; mt < 4; ++mt) {
#pragma unroll
        for (int nt = 0; nt < 4; ++nt) {
            const int c = col0 + wn + nt * 16 + l15;
#pragma unroll
            for (int r = 0; r < 4; ++r) {
                const int row = row0 + wm + mt * 16 + quad * 4 + r;
                C[(size_t)row * N + c] = f2bf(acc[mt][nt][r]);
            }
        }
    }
}

// ---------------- CSR gather aggregation (bf16 features, pre-scaled rows) ----
template <int F, bool RELU, bool OUTF32>
__global__ __launch_bounds__(256) void k_gather(
    const int* __restrict__ row_start, const int* __restrict__ csr_src,
    const float* __restrict__ dinv, const unsigned short* __restrict__ h,
    const float* __restrict__ bias, unsigned short* __restrict__ ob,
    float* __restrict__ of, int N) {
    const int gid  = blockIdx.x * blockDim.x + threadIdx.x;
    const int node = gid >> 6;
    const int lane = gid & 63;
    if (node >= N) return;

    constexpr int EL = F / 64;           // 4 (F=256) or 2 (F=128)
    const float wd = dinv[node];
    const int jb = row_start[node];
    const int je = row_start[node + 1];
    const unsigned short* hl = h + (size_t)lane * EL;

    float acc[EL];
    {   // self-loop term (h already dinv-scaled)
        const unsigned short* hp = hl + (size_t)node * F;
        if (EL == 4) {
            const ushort4 v = *(const ushort4*)hp;
            acc[0] = bf2f(v.x); acc[1] = bf2f(v.y);
            acc[2] = bf2f(v.z); acc[3] = bf2f(v.w);
        } else {
            const ushort2 v = *(const ushort2*)hp;
            acc[0] = bf2f(v.x); acc[1] = bf2f(v.y);
        }
    }

    for (int j0 = jb; j0 < je; j0 += 64) {
        int jj = j0 + lane;
        if (jj >= je) jj = je - 1;
        const int myi = csr_src[jj];
        const int rem = je - j0;
        const int cnt = rem < 64 ? rem : 64;
        int i = 0;
        for (; i + 4 <= cnt; i += 4) {   // 4 independent row loads in flight
            const int s0 = __shfl(myi, i + 0);
            const int s1 = __shfl(myi, i + 1);
            const int s2 = __shfl(myi, i + 2);
            const int s3 = __shfl(myi, i + 3);
            if (EL == 4) {
                const ushort4 v0 = *(const ushort4*)(hl + (size_t)s0 * F);
                const ushort4 v1 = *(const ushort4*)(hl + (size_t)s1 * F);
                const ushort4 v2 = *(const ushort4*)(hl + (size_t)s2 * F);
                const ushort4 v3 = *(const ushort4*)(hl + (size_t)s3 * F);
                acc[0] += bf2f(v0.x) + bf2f(v1.x) + bf2f(v2.x) + bf2f(v3.x);
                acc[1] += bf2f(v0.y) + bf2f(v1.y) + bf2f(v2.y) + bf2f(v3.y);
                acc[2] += bf2f(v0.z) + bf2f(v1.z) + bf2f(v2.z) + bf2f(v3.z);
                acc[3] += bf2f(v0.w) + bf2f(v1.w) + bf2f(v2.w) + bf2f(v3.w);
            } else {
                const ushort2 v0 = *(const ushort2*)(hl + (size_t)s0 * F);
                const ushort2 v1 = *(const ushort2*)(hl + (size_t)s1 * F);
                const ushort2 v2 = *(const ushort2*)(hl + (size_t)s2 * F);
                const ushort2 v3 = *(const ushort2*)(hl + (size_t)s3 * F);
                acc[0] += bf2f(v0.x) + bf2f(v1.x) + bf2f(v2.x) + bf2f(v3.x);
                acc[1] += bf2f(v0.y) + bf2f(v1.y) + bf2f(v2.y) + bf2f(v3.y);
            }
        }
        for (; i < cnt; ++i) {
            const int s = __shfl(myi, i);
            const unsigned short* hp = hl + (size_t)s * F;
            if (EL == 4) {
                const ushort4 v = *(const ushort4*)hp;
                acc[0] += bf2f(v.x); acc[1] += bf2f(v.y);
                acc[2] += bf2f(v.z); acc[3] += bf2f(v.w);
            } else {
                const ushort2 v = *(const ushort2*)hp;
                acc[0] += bf2f(v.x); acc[1] += bf2f(v.y);
            }
        }
    }

#pragma unroll
    for (int i = 0; i < EL; ++i) {
        float v = fmaf(acc[i], wd, bias[lane * EL + i]);
        if (OUTF32) {
            of[(size_t)node * F + lane * EL + i] = v;
        } else {
            if (RELU) v = fmaxf(v, 0.f);
            ob[(size_t)node * F + lane * EL + i] = f2bf(v * wd);  // pre-scale for next layer
        }
    }
}

extern "C" void kernel_launch(void* const* d_in, const int* in_sizes, int n_in,
                              void* d_out, int out_size, void* d_ws, size_t ws_size,
                              hipStream_t stream) {
    const float* x   = (const float*)d_in[0];
    const int*   ei  = (const int*)d_in[1];
    const float* W1  = (const float*)d_in[2];
    const float* b1  = (const float*)d_in[3];
    const float* W2  = (const float*)d_in[4];
    const float* b2  = (const float*)d_in[5];
    float*       out = (float*)d_out;

    const int N = in_sizes[0] / NFEAT;           // 50000
    const int E = in_sizes[1] / 2;               // 800000
    const int Mp = ((N + 127) / 128) * 128;      // 50048
    const int* srcp = ei;
    const int* dstp = ei + E;
    const int nScanBlocks = (N + SCAN_TILE - 1) / SCAN_TILE;   // 49
    const int CE = (E + P_CHUNKS - 1) / P_CHUNKS;              // 6250

    // workspace layout (256B aligned chunks)
    char* wsb = (char*)d_ws;
    auto take = [&](size_t bytes) {
        char* p = wsb;
        wsb += (bytes + 255) & ~(size_t)255;
        return p;
    };
    int*   degi      = (int*)take((size_t)N * 4);
    int*   row_start = (int*)take((size_t)(N + 1) * 4);
    int*   csr_src   = (int*)take((size_t)E * 4);
    int*   blocksums = (int*)take((size_t)1024 * 4);
    int*   blockoffs = (int*)take((size_t)1024 * 4);
    float* dinv      = (float*)take((size_t)N * 4);
    unsigned short* h2r = (unsigned short*)take((size_t)Mp * NFEAT * 2);  // h2 region
    unsigned short* W1t = (unsigned short*)take((size_t)NH1 * NFEAT * 2);
    unsigned short* W2t = (unsigned short*)take((size_t)NH2 * NH1 * 2);
    // union region: hist (25.7 MB, dead before GEMM1) overlaps h + h1 (51.2 MB)
    const size_t hBytes    = (size_t)Mp * NH1 * 2;
    const size_t histBytes = (size_t)P_CHUNKS * NP * 4;
    char* big = take(histBytes > 2 * hBytes ? histBytes : 2 * hBytes);
    int*            hist = (int*)big;
    unsigned short* h    = (unsigned short*)big;
    unsigned short* h1   = (unsigned short*)(big + hBytes);
    unsigned short* h2   = h2r;

    // ---- CSR build (atomic-free) + dinv ----
    k_hist<<<P_CHUNKS * 2, 256, 0, stream>>>(dstp, hist, E, CE);
    k_colreduce<<<(N + 255) / 256, 256, 0, stream>>>(hist, degi, dinv, N);
    k_scan1<<<nScanBlocks, SCAN_BLOCK, 0, stream>>>(degi, blocksums, N);
    k_scan2<<<1, 1024, 0, stream>>>(blocksums, blockoffs, row_start, nScanBlocks, N);
    k_scan3<<<nScanBlocks, SCAN_BLOCK, 0, stream>>>(degi, blockoffs, row_start, N);
    k_coloffs<<<(N + 255) / 256, 256, 0, stream>>>(hist, row_start, N);
    k_place<<<P_CHUNKS * 2, 256, 0, stream>>>(srcp, dstp, hist, csr_src, E, CE);

    // ---- weight conversion (one dispatch) ----
    {
        const int total = NFEAT * NH1 + NH1 * NH2;
        k_cvt_w<<<(total + 255) / 256, 256, 0, stream>>>(W1, W1t, W2, W2t);
    }

    // ---- layer 1: h = (x*dinv)@W1 fused (bf16) ; h1 = relu(...)*dinv (bf16) ----
    gemm_x_fused<<<Mp / 128, 512, 0, stream>>>(x, dinv, W1t, h, N, NFEAT);
    {
        int total = N * 64;
        k_gather<NH1, true, false><<<(total + 255) / 256, 256, 0, stream>>>(
            row_start, csr_src, dinv, h, b1, h1, nullptr, N);
    }

    // ---- layer 2: h2 = h1s@W2 (bf16) ; out = gather + b2 (fp32) ----
    {
        dim3 g(NH2 / 128, Mp / 128);
        gemm_bf16<<<g, 256, 0, stream>>>(h1, W2t, h2, NH2, NH1);
    }
    {
        int total = N * 64;
        k_gather<NH2, false, true><<<(total + 255) / 256, 256, 0, stream>>>(
            row_start, csr_src, dinv, h2, b2, nullptr, out, N);
    }
}